// Round 1
// baseline (201.861 us; speedup 1.0000x reference)
//
#include <hip/hip_runtime.h>
#include <cstdint>
#include <cstddef>

using bf16 = __bf16;
typedef float f32x4 __attribute__((ext_vector_type(4)));
typedef __bf16 bf16x8v __attribute__((ext_vector_type(8)));
typedef __bf16 bf16x4v __attribute__((ext_vector_type(4)));

// Problem constants: B=4, S=2048, D=1024
#define NX   8388608      // 4*2048*1024 elements of x / q / k / v
#define NW   1048576      // 1024*1024 per weight matrix
#define SB   2048
#define DD   1024

__device__ __forceinline__ void gload_lds16(const bf16* g, bf16* l) {
    __builtin_amdgcn_global_load_lds(
        (const __attribute__((address_space(1))) void*)(g),
        (__attribute__((address_space(3))) void*)(l), 16, 0, 0);
}

// ---------------------------------------------------------------------------
// Convert fp32 inputs -> bf16 in workspace; copy biases (fp32) contiguous.
// ---------------------------------------------------------------------------
__global__ __launch_bounds__(256)
void convert_kernel(const float* __restrict__ x1,
                    const float* __restrict__ Wq, const float* __restrict__ Wk,
                    const float* __restrict__ Wv,
                    const float* __restrict__ bq, const float* __restrict__ bk,
                    const float* __restrict__ bv,
                    bf16* __restrict__ xb, bf16* __restrict__ wb,
                    float* __restrict__ biases)
{
    const int NX4 = NX / 4;       // 2097152
    const int NW4 = NW / 4;       // 262144
    const int NMAT = NX4 + 3 * NW4;
    const int total = NMAT + 768; // + bias float4 groups (3*1024/4)
    for (int i = blockIdx.x * 256 + threadIdx.x; i < total; i += gridDim.x * 256) {
        if (i < NMAT) {
            const float* src; bf16* dst; int j;
            if (i < NX4) { src = x1; dst = xb; j = i; }
            else {
                int w = (i - NX4) / NW4;
                j = (i - NX4) - w * NW4;
                src = (w == 0) ? Wq : (w == 1) ? Wk : Wv;
                dst = wb + (size_t)w * NW;
            }
            float4 f = ((const float4*)src)[j];
            bf16x4v o;
            o[0] = (bf16)f.x; o[1] = (bf16)f.y; o[2] = (bf16)f.z; o[3] = (bf16)f.w;
            ((bf16x4v*)dst)[j] = o;
        } else {
            int j = i - NMAT; // 0..767
            const float* src = (j < 256) ? bq : (j < 512) ? bk : bv;
            ((float4*)biases)[j] = ((const float4*)src)[j & 255];
        }
    }
}

// ---------------------------------------------------------------------------
// GEMM: C[m][n] = scale * sum_k A[m][k]*B[n][k] (+ bias[n])
// A: M x K row-major bf16, B: N x K row-major bf16 (both K-contiguous).
// 128x128 tile, BK=64, 4 waves (2x2 of 64x64), mfma_f32_16x16x32_bf16.
// LDS XOR-swizzle (chunk ^= row&7) applied on the global SOURCE address
// (linear LDS dest for global_load_lds) and on the ds_read address.
// TRANS: write V^T layout [batch][D][S] (batch = m>>11, s = m&2047).
// ---------------------------------------------------------------------------
template<bool BIAS, bool TRANS, typename OutT>
__global__ __launch_bounds__(256)
void gemm_bt(const bf16* __restrict__ A, const bf16* __restrict__ B,
             OutT* __restrict__ C, const float* __restrict__ bias,
             int N, int K,
             long sAz, long sBz, long sCz, long sBiasz, float scale)
{
    __shared__ bf16 lA[128 * 64];
    __shared__ bf16 lB[128 * 64];
    const int z = blockIdx.z;
    A += (size_t)z * sAz;
    B += (size_t)z * sBz;
    C += (size_t)z * sCz;
    const float* bptr = bias ? bias + (size_t)z * sBiasz : nullptr;

    const int n0 = blockIdx.x * 128;
    const int m0 = blockIdx.y * 128;
    const int t = threadIdx.x;
    const int lane = t & 63;
    const int wid = t >> 6;
    const int wr = wid >> 1, wc = wid & 1;

    f32x4 acc[4][4];
    #pragma unroll
    for (int m = 0; m < 4; ++m)
        #pragma unroll
        for (int n = 0; n < 4; ++n) acc[m][n] = (f32x4){0.f, 0.f, 0.f, 0.f};

    for (int k0 = 0; k0 < K; k0 += 64) {
        // stage A,B tiles: 128 rows x 64 cols bf16 each; 16B per lane per round
        #pragma unroll
        for (int l = 0; l < 4; ++l) {
            const int idx = l * 256 + t;
            const int row = idx >> 3;
            const int c   = idx & 7;
            const int gc  = c ^ (row & 7);   // inverse-swizzled source chunk
            gload_lds16(A + (size_t)(m0 + row) * K + k0 + gc * 8, &lA[idx * 8]);
            gload_lds16(B + (size_t)(n0 + row) * K + k0 + gc * 8, &lB[idx * 8]);
        }
        __syncthreads();
        #pragma unroll
        for (int kk = 0; kk < 2; ++kk) {
            bf16x8v af[4], bfr[4];
            #pragma unroll
            for (int m = 0; m < 4; ++m) {
                const int row = wr * 64 + m * 16 + (lane & 15);
                const int ch  = (kk * 4 + (lane >> 4)) ^ (row & 7);
                af[m] = *(const bf16x8v*)&lA[row * 64 + ch * 8];
            }
            #pragma unroll
            for (int n = 0; n < 4; ++n) {
                const int row = wc * 64 + n * 16 + (lane & 15);
                const int ch  = (kk * 4 + (lane >> 4)) ^ (row & 7);
                bfr[n] = *(const bf16x8v*)&lB[row * 64 + ch * 8];
            }
            #pragma unroll
            for (int m = 0; m < 4; ++m)
                #pragma unroll
                for (int n = 0; n < 4; ++n)
                    acc[m][n] = __builtin_amdgcn_mfma_f32_16x16x32_bf16(
                        af[m], bfr[n], acc[m][n], 0, 0, 0);
        }
        __syncthreads();
    }

    // epilogue: C/D map col=lane&15, row=(lane>>4)*4+reg (m89-verified)
    const int cif = lane & 15;
    const int rif = (lane >> 4) << 2;
    #pragma unroll
    for (int m = 0; m < 4; ++m) {
        const int rb = m0 + wr * 64 + m * 16 + rif;
        #pragma unroll
        for (int n = 0; n < 4; ++n) {
            const int c = n0 + wc * 64 + n * 16 + cif;
            const float bv = BIAS ? bptr[c] : 0.0f;
            if constexpr (!TRANS) {
                #pragma unroll
                for (int r = 0; r < 4; ++r) {
                    const float val = acc[m][n][r] * scale + bv;
                    C[(size_t)(rb + r) * N + c] = (OutT)val;
                }
            } else {
                const int batch = rb >> 11;
                const int s = rb & 2047;
                typedef OutT OutV __attribute__((ext_vector_type(4)));
                OutV pk;
                #pragma unroll
                for (int r = 0; r < 4; ++r)
                    pk[r] = (OutT)(acc[m][n][r] * scale + bv);
                *(OutV*)&C[((size_t)batch << 21) + ((size_t)c << 11) + s] = pk;
            }
        }
    }
}

// ---------------------------------------------------------------------------
// Row softmax in-place over bf16 scores; rows of length 2048, 1 block/row.
// ---------------------------------------------------------------------------
__global__ __launch_bounds__(256)
void softmax_inplace(bf16* __restrict__ sc)
{
    __shared__ float red[8];
    bf16* row = sc + (size_t)blockIdx.x * 2048;
    const int t = threadIdx.x;
    const int lane = t & 63;
    const int wid = t >> 6;

    bf16x8v v = *(const bf16x8v*)(row + t * 8);
    float f[8];
    #pragma unroll
    for (int j = 0; j < 8; ++j) f[j] = (float)v[j];

    float m = f[0];
    #pragma unroll
    for (int j = 1; j < 8; ++j) m = fmaxf(m, f[j]);
    #pragma unroll
    for (int off = 32; off >= 1; off >>= 1) m = fmaxf(m, __shfl_xor(m, off));
    if (lane == 0) red[wid] = m;
    __syncthreads();
    m = fmaxf(fmaxf(red[0], red[1]), fmaxf(red[2], red[3]));

    float s = 0.f;
    #pragma unroll
    for (int j = 0; j < 8; ++j) { f[j] = __expf(f[j] - m); s += f[j]; }
    #pragma unroll
    for (int off = 32; off >= 1; off >>= 1) s += __shfl_xor(s, off);
    if (lane == 0) red[4 + wid] = s;
    __syncthreads();
    s = red[4] + red[5] + red[6] + red[7];

    const float inv = 1.0f / s;
    bf16x8v o;
    #pragma unroll
    for (int j = 0; j < 8; ++j) o[j] = (bf16)(f[j] * inv);
    *(bf16x8v*)(row + t * 8) = o;
}

// ---------------------------------------------------------------------------
extern "C" void kernel_launch(void* const* d_in, const int* in_sizes, int n_in,
                              void* d_out, int out_size, void* d_ws, size_t ws_size,
                              hipStream_t stream)
{
    const float* x1 = (const float*)d_in[0];
    const float* Wq = (const float*)d_in[1];
    const float* bq = (const float*)d_in[2];
    const float* Wk = (const float*)d_in[3];
    const float* bk = (const float*)d_in[4];
    const float* Wv = (const float*)d_in[5];
    const float* bv = (const float*)d_in[6];
    float* out = (float*)d_out;

    // workspace layout (bf16 elements unless noted)
    bf16* xb     = (bf16*)d_ws;             // 8388608
    bf16* wb     = xb + NX;                 // 3*1048576
    bf16* qkb    = wb + 3 * NW;             // 2*8388608 (q then k)
    bf16* vTb    = qkb + 2 * (size_t)NX;    // 8388608 (V^T per batch [D][S])
    bf16* scores = vTb + NX;                // 4*2048*2048
    float* biases = (float*)(scores + 4 * (size_t)SB * SB); // 3072 f32

    // 1. convert inputs to bf16
    convert_kernel<<<dim3(2048), dim3(256), 0, stream>>>(
        x1, Wq, Wk, Wv, bq, bk, bv, xb, wb, biases);

    // 2a. q,k projections: M=8192, N=1024, K=1024, z=2 (q,k)
    gemm_bt<true, false, bf16><<<dim3(8, 64, 2), dim3(256), 0, stream>>>(
        xb, wb, qkb, biases, DD, DD,
        0L, (long)NW, (long)NX, 1024L, 1.0f);

    // 2b. v projection, transposed output per batch [D][S]
    gemm_bt<true, true, bf16><<<dim3(8, 64, 1), dim3(256), 0, stream>>>(
        xb, wb + 2 * (size_t)NW, vTb, biases + 2048, DD, DD,
        0L, 0L, 0L, 0L, 1.0f);

    // 3. scores = Q K^T / 32 per batch: M=N=2048, K=1024, z=4
    gemm_bt<false, false, bf16><<<dim3(16, 16, 4), dim3(256), 0, stream>>>(
        qkb, qkb + NX, scores, nullptr, SB, DD,
        (long)(SB * DD), (long)(SB * DD), (long)(SB * SB), 0L, 1.0f / 32.0f);

    // 4. softmax rows in-place
    softmax_inplace<<<dim3(4 * SB), dim3(256), 0, stream>>>(scores);

    // 5. out = P V per batch: M=2048, N=1024, K=2048, z=4, fp32 out
    gemm_bt<false, false, float><<<dim3(8, 16, 4), dim3(256), 0, stream>>>(
        scores, vTb, out, nullptr, DD, SB,
        (long)(SB * SB), (long)(SB * DD), (long)(SB * DD), 0L, 1.0f);
}